// Round 7
// baseline (1142.116 us; speedup 1.0000x reference)
//
#include <hip/hip_runtime.h>

// RWKV WKV forward — R11: decoupled-lookback chained scan, 1024-B runs.
// (R10 + compile fix: native ext_vector float4 for nontemporal builtins.)
//
// Identity: with P=(num,den) scaled by 2^m, the step is the linear recurrence
// P' = 2^{tds} P + 2^{kts} (v,1), decay channel-constant => associative.
//
// Why: R5-R9 (5 structural variants) all pin at 403 MB serviced / ~130 us
// ~= 3.1 TB/s — including R8's spill run (889 MB/288 us = 3.09 TB/s). The
// invariant across all: 256-B contiguous chunks at 8-KiB stride (64 ch x
// 4 B per row). Theory: DRAM efficiency is bound by contiguous run length
// per strided visit. R11 widens runs to 1024 B (256 ch per wave, float4
// per lane), which forces the sequence to be split ACROSS blocks:
//   chain = (batch, H-half), 16 chains x 256 chunks of 8 steps.
//   Block(chain,i): load its 8 rows (k,v) to REGISTERS (float4), phase A
//   local scan, publish aggregate (flag=1), decoupled lookback over
//   predecessors' records to get the incoming state, publish inclusive
//   (flag=2), replay outputs from registers.
// Safety: bid = i*nchain + chain => predecessor bid strictly lower (no
// dispatch-order deadlock); bounded spin (SPINM) then self-recompute of
// the predecessor aggregate => finite work under ANY scheduling. Records
// use agent-scope atomics (cross-XCD safe). bid%nchain pins each chain to
// one XCD => record/flag traffic is L2-local.
// Fallback: verified R9 blocked kernel if ws too small / shapes odd.

#define LCH   8             // steps per chunk
#define CPB   4             // channels per thread (float4)
#define THR   256           // threads per block
#define GCH   1024          // THR*CPB channels per chain
#define SPINM 65536

typedef float f4v __attribute__((ext_vector_type(4)));   // native vector:
// accepted by __builtin_nontemporal_load/store (HIP float4 class is not).

__device__ __forceinline__ float ex2(float x)  { return __builtin_amdgcn_exp2f(x); }
__device__ __forceinline__ float rcpf(float x) { return __builtin_amdgcn_rcpf(x); }

// Combine: (M,N,D) := left ⊕ right, where left=(M,N,D), right=(sm,sn,sd),
// dlen = tds * (span of right). Overwrites left with the result.
__device__ __forceinline__ void merge1(float& M, float& N, float& D,
                                       float dlen, float sm, float sn, float sd)
{
    const float Md = M + dlen;
    const float d  = Md - sm;
    const float e  = ex2(-fabsf(d));
    const bool  c  = d >= 0.f;
    const float a  = c ? 1.f : e;
    const float bb = c ? e : 1.f;
    N = a * N + bb * sn;
    D = a * D + bb * sd;
    M = fmaxf(Md, sm);
}

__global__ __launch_bounds__(THR, 4)
void wkv_fwd_lb(const float* __restrict__ td_in, const float* __restrict__ kin,
                const float* __restrict__ tf_in, const float* __restrict__ vin,
                const float* __restrict__ m0, const float* __restrict__ n0,
                const float* __restrict__ d0,
                float* __restrict__ out, float* __restrict__ m_out,
                float* __restrict__ n_out, float* __restrict__ dn_out,
                int* __restrict__ flags,
                float* __restrict__ agm, float* __restrict__ agn, float* __restrict__ agd,
                float* __restrict__ icm, float* __restrict__ icn, float* __restrict__ icd,
                int B, int S, int H, int nchain, int NC)
{
    __shared__ int shf;
    const int tid   = threadIdx.x;
    const int bid   = blockIdx.x;
    const int chain = bid % nchain;          // XCD-local per chain
    const int i     = bid / nchain;          // chunk index (pred bid < bid)
    const int hgpb  = H / GCH;
    const int b     = chain / hgpb;
    const int hg    = chain - b * hgpb;
    const int ch    = hg * GCH + tid * CPB;  // first of this thread's 4 ch
    const int g0    = b * H + ch;

    constexpr float Cc = 1.4426950408889634f;   // log2(e)
    constexpr float IC = 0.6931471805599453f;   // ln(2)

    float tds[CPB], tfs[CPB];
    {
        const f4v t4 = *reinterpret_cast<const f4v*>(td_in + ch);
        const f4v f4 = *reinterpret_cast<const f4v*>(tf_in + ch);
        #pragma unroll
        for (int c = 0; c < CPB; ++c) {
            tds[c] = -ex2(t4[c] * Cc) * Cc;
            tfs[c] = f4[c] * Cc;
        }
    }

    // ---- Bulk load: 8 (k,v) rows, 1024-B contiguous per wave-instruction.
    const size_t rowbase = ((size_t)b * S + (size_t)i * LCH) * H + ch;
    f4v kq[LCH], vq[LCH];
    #pragma unroll
    for (int j = 0; j < LCH; ++j) {
        kq[j] = __builtin_nontemporal_load(
                    reinterpret_cast<const f4v*>(kin + rowbase + (size_t)j * H));
        vq[j] = __builtin_nontemporal_load(
                    reinterpret_cast<const f4v*>(vin + rowbase + (size_t)j * H));
    }

    // ---- Phase A: local scan (neutral init), 4 independent channel chains.
    float lm[CPB], ln[CPB], ld[CPB];
    #pragma unroll
    for (int c = 0; c < CPB; ++c) { lm[c] = -1e30f; ln[c] = 0.f; ld[c] = 0.f; }
    #pragma unroll
    for (int j = 0; j < LCH; ++j) {
        #pragma unroll
        for (int c = 0; c < CPB; ++c) {
            const float kt  = kq[j][c] * Cc;
            const float vt  = vq[j][c];
            const float mpd = lm[c] + tds[c];
            const float d   = mpd - kt;            // max-trick
            const float e   = ex2(-fabsf(d));
            const bool  cc  = d >= 0.f;
            const float e1  = cc ? 1.f : e;
            const float e2  = cc ? e : 1.f;
            ln[c] = e1 * ln[c] + e2 * vt;
            ld[c] = e1 * ld[c] + e2;
            lm[c] = fmaxf(mpd, kt);
        }
    }

    const size_t myoff = (size_t)bid * GCH + (size_t)tid * CPB;

    // ---- Publish aggregate (only chunks with successors; i==0 goes
    //      straight to inclusive).
    if (i > 0 && i < NC - 1) {
        #pragma unroll
        for (int c = 0; c < CPB; ++c) {
            __hip_atomic_store(agm + myoff + c, lm[c], __ATOMIC_RELAXED, __HIP_MEMORY_SCOPE_AGENT);
            __hip_atomic_store(agn + myoff + c, ln[c], __ATOMIC_RELAXED, __HIP_MEMORY_SCOPE_AGENT);
            __hip_atomic_store(agd + myoff + c, ld[c], __ATOMIC_RELAXED, __HIP_MEMORY_SCOPE_AGENT);
        }
        __syncthreads();                      // all stores drained
        if (tid == 0)
            __hip_atomic_store(flags + bid, 1, __ATOMIC_RELEASE, __HIP_MEMORY_SCOPE_AGENT);
    }

    // ---- Lookback: before-state (bM,bN,bD). Suffix accumulates in bM..
    float bM[CPB], bN[CPB], bD[CPB];
    if (i == 0) {
        const f4v a4 = *reinterpret_cast<const f4v*>(m0 + g0);
        const f4v b4 = *reinterpret_cast<const f4v*>(n0 + g0);
        const f4v c4 = *reinterpret_cast<const f4v*>(d0 + g0);
        #pragma unroll
        for (int c = 0; c < CPB; ++c) {
            bM[c] = a4[c] * Cc; bN[c] = b4[c]; bD[c] = c4[c];
        }
    } else {
        #pragma unroll
        for (int c = 0; c < CPB; ++c) { bM[c] = -1e30f; bN[c] = 0.f; bD[c] = 0.f; }
        int cnt = 0, pred = i - 1;
        bool done = false;
        while (!done) {
            if (tid == 0) {
                int ff, t = 0;
                do {
                    ff = __hip_atomic_load(flags + ((size_t)pred * nchain + chain),
                                           __ATOMIC_ACQUIRE, __HIP_MEMORY_SCOPE_AGENT);
                } while (ff == 0 && ++t < SPINM);
                shf = ff;
            }
            __syncthreads();
            const int f2 = shf;
            __syncthreads();
            const size_t poff = ((size_t)pred * nchain + chain) * GCH + (size_t)tid * CPB;
            float am[CPB], an[CPB], ad[CPB];
            if (f2 == 2) {                    // inclusive found: prepend & stop
                #pragma unroll
                for (int c = 0; c < CPB; ++c) {
                    am[c] = __hip_atomic_load(icm + poff + c, __ATOMIC_RELAXED, __HIP_MEMORY_SCOPE_AGENT);
                    an[c] = __hip_atomic_load(icn + poff + c, __ATOMIC_RELAXED, __HIP_MEMORY_SCOPE_AGENT);
                    ad[c] = __hip_atomic_load(icd + poff + c, __ATOMIC_RELAXED, __HIP_MEMORY_SCOPE_AGENT);
                    merge1(am[c], an[c], ad[c], tds[c] * (float)(LCH * cnt), bM[c], bN[c], bD[c]);
                    bM[c] = am[c]; bN[c] = an[c]; bD[c] = ad[c];
                }
                done = true;
            } else {
                if (f2 == 1) {                // aggregate available
                    #pragma unroll
                    for (int c = 0; c < CPB; ++c) {
                        am[c] = __hip_atomic_load(agm + poff + c, __ATOMIC_RELAXED, __HIP_MEMORY_SCOPE_AGENT);
                        an[c] = __hip_atomic_load(agn + poff + c, __ATOMIC_RELAXED, __HIP_MEMORY_SCOPE_AGENT);
                        ad[c] = __hip_atomic_load(agd + poff + c, __ATOMIC_RELAXED, __HIP_MEMORY_SCOPE_AGENT);
                    }
                } else {                      // timeout: recompute pred's agg
                    #pragma unroll
                    for (int c = 0; c < CPB; ++c) { am[c] = -1e30f; an[c] = 0.f; ad[c] = 0.f; }
                    const size_t pb = ((size_t)b * S + (size_t)pred * LCH) * H + ch;
                    for (int j = 0; j < LCH; ++j) {
                        const f4v kk = *reinterpret_cast<const f4v*>(kin + pb + (size_t)j * H);
                        const f4v vv = *reinterpret_cast<const f4v*>(vin + pb + (size_t)j * H);
                        #pragma unroll
                        for (int c = 0; c < CPB; ++c) {
                            const float kt  = kk[c] * Cc;
                            const float vt  = vv[c];
                            const float mpd = am[c] + tds[c];
                            const float d   = mpd - kt;
                            const float e   = ex2(-fabsf(d));
                            const bool  cc  = d >= 0.f;
                            const float e1  = cc ? 1.f : e;
                            const float e2  = cc ? e : 1.f;
                            an[c] = e1 * an[c] + e2 * vt;
                            ad[c] = e1 * ad[c] + e2;
                            am[c] = fmaxf(mpd, kt);
                        }
                    }
                }
                #pragma unroll
                for (int c = 0; c < CPB; ++c) {   // suffix = agg ⊕ suffix
                    merge1(am[c], an[c], ad[c], tds[c] * (float)(LCH * cnt), bM[c], bN[c], bD[c]);
                    bM[c] = am[c]; bN[c] = an[c]; bD[c] = ad[c];
                }
                ++cnt; --pred;
                if (pred < 0) {               // hit chain start: prepend init
                    const f4v a4 = *reinterpret_cast<const f4v*>(m0 + g0);
                    const f4v b4 = *reinterpret_cast<const f4v*>(n0 + g0);
                    const f4v c4 = *reinterpret_cast<const f4v*>(d0 + g0);
                    #pragma unroll
                    for (int c = 0; c < CPB; ++c) {
                        am[c] = a4[c] * Cc; an[c] = b4[c]; ad[c] = c4[c];
                        merge1(am[c], an[c], ad[c], tds[c] * (float)(LCH * cnt), bM[c], bN[c], bD[c]);
                        bM[c] = am[c]; bN[c] = an[c]; bD[c] = ad[c];
                    }
                    done = true;
                }
            }
        }
    }

    // ---- Inclusive = before ⊕ own aggregate; publish or emit final state.
    {
        float iM[CPB], iN[CPB], iD[CPB];
        #pragma unroll
        for (int c = 0; c < CPB; ++c) {
            iM[c] = bM[c]; iN[c] = bN[c]; iD[c] = bD[c];
            merge1(iM[c], iN[c], iD[c], tds[c] * (float)LCH, lm[c], ln[c], ld[c]);
        }
        if (i < NC - 1) {
            #pragma unroll
            for (int c = 0; c < CPB; ++c) {
                __hip_atomic_store(icm + myoff + c, iM[c], __ATOMIC_RELAXED, __HIP_MEMORY_SCOPE_AGENT);
                __hip_atomic_store(icn + myoff + c, iN[c], __ATOMIC_RELAXED, __HIP_MEMORY_SCOPE_AGENT);
                __hip_atomic_store(icd + myoff + c, iD[c], __ATOMIC_RELAXED, __HIP_MEMORY_SCOPE_AGENT);
            }
            __syncthreads();
            if (tid == 0)
                __hip_atomic_store(flags + bid, 2, __ATOMIC_RELEASE, __HIP_MEMORY_SCOPE_AGENT);
        } else {
            f4v a4, b4, c4;
            #pragma unroll
            for (int c = 0; c < CPB; ++c) {
                a4[c] = iM[c] * IC; b4[c] = iN[c]; c4[c] = iD[c];
            }
            *reinterpret_cast<f4v*>(m_out  + g0) = a4;
            *reinterpret_cast<f4v*>(n_out  + g0) = b4;
            *reinterpret_cast<f4v*>(dn_out + g0) = c4;
        }
    }

    // ---- Phase B: replay outputs from registers (1024-B stores).
    #pragma unroll
    for (int j = 0; j < LCH; ++j) {
        f4v o4;
        #pragma unroll
        for (int c = 0; c < CPB; ++c) {
            const float kt  = kq[j][c] * Cc;
            const float vt  = vq[j][c];
            const float ktf = kt + tfs[c];
            const float dd  = bM[c] - ktf;
            const float eo  = ex2(-fabsf(dd));
            const bool  co  = dd >= 0.f;
            const float e1o = co ? 1.f : eo;
            const float e2o = co ? eo : 1.f;
            o4[c] = (e1o * bN[c] + e2o * vt) * rcpf(fmaf(e1o, bD[c], e2o));
            const float mpd = bM[c] + tds[c];
            const float ds  = mpd - kt;
            const float es  = ex2(-fabsf(ds));
            const bool  cs  = ds >= 0.f;
            const float e1s = cs ? 1.f : es;
            const float e2s = cs ? es : 1.f;
            bN[c] = e1s * bN[c] + e2s * vt;
            bD[c] = e1s * bD[c] + e2s;
            bM[c] = fmaxf(mpd, kt);
        }
        __builtin_nontemporal_store(o4,
            reinterpret_cast<f4v*>(out + rowbase + (size_t)j * H));
    }
}

// ======================= R9 fallback (verified, 134 us) ====================
#define BTILE   128
#define BNW     8
#define BWSTEPS 16
#define BSUBL   8
#define BARR  asm volatile("s_waitcnt lgkmcnt(0)\n\ts_barrier" ::: "memory")

__global__ __launch_bounds__(512, 4)
void wkv_fwd_blocked(const float* __restrict__ td_in, const float* __restrict__ kin,
                     const float* __restrict__ tf_in, const float* __restrict__ vin,
                     const float* __restrict__ m0, const float* __restrict__ n0,
                     const float* __restrict__ d0,
                     float* __restrict__ out, float* __restrict__ m_out,
                     float* __restrict__ n_out, float* __restrict__ dn_out,
                     int B, int S, int H)
{
    __shared__ float smry[2][BNW][3][32];
    __shared__ float cry[2][3][32];

    const int tid  = threadIdx.x;
    const int lane = tid & 63;
    const int w    = tid >> 6;
    const int c    = lane & 31;
    const int s    = lane >> 5;

    const int bpb = H >> 5;
    const int b   = blockIdx.x / bpb;
    const int hb  = (blockIdx.x - b * bpb) << 5;
    const int h   = hb + c;
    const int g   = b * H + h;

    constexpr float Cc = 1.4426950408889634f;
    constexpr float IC = 0.6931471805599453f;

    const float tds    = -ex2(td_in[h] * Cc) * Cc;
    const float tfs    = tf_in[h] * Cc;
    const float dseg8  = tds * (float)BSUBL;
    const float dseg16 = tds * (float)BWSTEPS;

    if (w == 0 && s == 0) {
        cry[0][0][c] = m0[g] * Cc;
        cry[0][1][c] = n0[g];
        cry[0][2][c] = d0[g];
    }

    const size_t base = (size_t)b * (size_t)S * (size_t)H + (size_t)hb;
    const float* gk = kin + base;
    const float* gv = vin + base;
    float*       go = out + base;

    const int row0   = w * BWSTEPS + s * BSUBL;
    const int ntiles = S / BTILE;

    float fM = 0.f, fN = 0.f, fD = 0.f;
    float ka[BSUBL], va[BSUBL], kb[BSUBL], vb[BSUBL];

    #pragma unroll
    for (int j = 0; j < BSUBL; ++j) {
        ka[j] = gk[(size_t)(row0 + j) * (size_t)H + c];
        va[j] = gv[(size_t)(row0 + j) * (size_t)H + c];
    }

    auto body = [&](int it, float (&ck)[BSUBL], float (&cv)[BSUBL],
                    float (&nk)[BSUBL], float (&nv)[BSUBL])
                __attribute__((always_inline)) -> void {
        if (it + 1 < ntiles) {
            const size_t r1 = (size_t)(it + 1) * BTILE + row0;
            #pragma unroll
            for (int j = 0; j < BSUBL; ++j) {
                nk[j] = gk[(r1 + j) * (size_t)H + c];
                nv[j] = gv[(r1 + j) * (size_t)H + c];
            }
        }
        const int p = it & 1;
        float lm = -1e30f, ln = 0.f, ld = 0.f;
        #pragma unroll
        for (int j = 0; j < BSUBL; ++j) {
            const float kt = ck[j] * Cc;
            ck[j] = kt;
            const float vt  = cv[j];
            const float mpd = lm + tds;
            const float d   = mpd - kt;
            const float e   = ex2(-fabsf(d));
            const bool  cc  = d >= 0.f;
            const float e1  = cc ? 1.f : e;
            const float e2  = cc ? e : 1.f;
            ln = e1 * ln + e2 * vt;
            ld = e1 * ld + e2;
            lm = fmaxf(mpd, kt);
        }
        const float om = __shfl_xor(lm, 32);
        const float on = __shfl_xor(ln, 32);
        const float od = __shfl_xor(ld, 32);
        float wm = s ? om : lm, wn = s ? on : ln, wd = s ? od : ld;
        {
            const float sm2 = s ? lm : om;
            const float sn2 = s ? ln : on;
            const float sd2 = s ? ld : od;
            merge1(wm, wn, wd, dseg8, sm2, sn2, sd2);
        }
        if (s == 0) {
            smry[p][w][0][c] = wm;
            smry[p][w][1][c] = wn;
            smry[p][w][2][c] = wd;
        }
        BARR;
        float M = cry[p][0][c];
        float N = cry[p][1][c];
        float D = cry[p][2][c];
        #pragma unroll
        for (int j = 0; j < BNW - 1; ++j) {
            const float sm = smry[p][j][0][c];
            const float sn = smry[p][j][1][c];
            const float sd = smry[p][j][2][c];
            if (j < w) merge1(M, N, D, dseg16, sm, sn, sd);
        }
        if (w == BNW - 1 && s == 0) {
            fM = M; fN = N; fD = D;
            merge1(fM, fN, fD, dseg16, wm, wn, wd);
            cry[p ^ 1][0][c] = fM;
            cry[p ^ 1][1][c] = fN;
            cry[p ^ 1][2][c] = fD;
        }
        if (s == 1) merge1(M, N, D, dseg8, om, on, od);
        float* po = go + ((size_t)it * BTILE + row0) * (size_t)H;
        #pragma unroll
        for (int j = 0; j < BSUBL; ++j) {
            const float kt  = ck[j];
            const float vt  = cv[j];
            const float ktf = kt + tfs;
            const float dd  = M - ktf;
            const float eo  = ex2(-fabsf(dd));
            const bool  co  = dd >= 0.f;
            const float e1o = co ? 1.f : eo;
            const float e2o = co ? eo : 1.f;
            po[(size_t)j * H + c] =
                (e1o * N + e2o * vt) * rcpf(fmaf(e1o, D, e2o));
            const float mpd = M + tds;
            const float ds_ = mpd - kt;
            const float es  = ex2(-fabsf(ds_));
            const bool  cs  = ds_ >= 0.f;
            const float e1s = cs ? 1.f : es;
            const float e2s = cs ? es : 1.f;
            N = e1s * N + e2s * vt;
            D = e1s * D + e2s;
            M = fmaxf(mpd, kt);
        }
    };

    int it = 0;
    for (; it + 1 < ntiles; it += 2) {
        body(it,     ka, va, kb, vb);
        body(it + 1, kb, vb, ka, va);
    }
    if (it < ntiles) body(it, ka, va, kb, vb);

    if (w == BNW - 1 && s == 0) {
        m_out[g]  = fM * IC;
        n_out[g]  = fN;
        dn_out[g] = fD;
    }
}

// Safety fallback (serial per channel).
__global__ __launch_bounds__(64)
void wkv_fwd_serial(const float* __restrict__ td_in, const float* __restrict__ kin,
                    const float* __restrict__ tf_in, const float* __restrict__ vin,
                    const float* __restrict__ m0, const float* __restrict__ n0,
                    const float* __restrict__ d0,
                    float* __restrict__ out, float* __restrict__ m_out,
                    float* __restrict__ n_out, float* __restrict__ dn_out,
                    int B, int S, int H)
{
    const int g = blockIdx.x * 64 + threadIdx.x;
    if (g >= B * H) return;
    const int b = g / H;
    const int h = g - b * H;
    constexpr float Cc = 1.4426950408889634f, IC = 0.6931471805599453f;
    const float tds = -ex2(td_in[h] * Cc) * Cc;
    const float tfs = tf_in[h] * Cc;
    float M = m0[g] * Cc, N = n0[g], D = d0[g];
    const size_t base = (size_t)b * S * H + h;
    for (int t = 0; t < S; ++t) {
        const float kt  = kin[base + (size_t)t * H] * Cc;
        const float vt  = vin[base + (size_t)t * H];
        const float ktf = kt + tfs;
        const float mo  = fmaxf(M, ktf);
        const float e1o = ex2(M - mo), e2o = ex2(ktf - mo);
        out[base + (size_t)t * H] = (e1o * N + e2o * vt) * rcpf(e1o * D + e2o);
        const float mpd = M + tds;
        const float ms  = fmaxf(mpd, kt);
        const float e1s = ex2(mpd - ms), e2s = ex2(kt - ms);
        N = e1s * N + e2s * vt;
        D = e1s * D + e2s;
        M = ms;
    }
    m_out[g] = M * IC; n_out[g] = N; dn_out[g] = D;
}

extern "C" void kernel_launch(void* const* d_in, const int* in_sizes, int n_in,
                              void* d_out, int out_size, void* d_ws, size_t ws_size,
                              hipStream_t stream)
{
    const float* time_decay = (const float*)d_in[0];
    const float* key        = (const float*)d_in[1];
    const float* time_first = (const float*)d_in[2];
    const float* value      = (const float*)d_in[3];
    const float* max_state  = (const float*)d_in[4];
    const float* num_state  = (const float*)d_in[5];
    const float* den_state  = (const float*)d_in[6];

    const int H  = in_sizes[0];
    const int BH = in_sizes[4];
    const int B  = BH / H;
    const int S  = in_sizes[1] / BH;

    float* out    = (float*)d_out;
    float* m_out  = out + (size_t)B * (size_t)S * (size_t)H;
    float* n_out  = m_out + BH;
    float* dn_out = n_out + BH;

    bool launched = false;
    if ((H % GCH == 0) && (S % LCH == 0) && d_ws != nullptr) {
        const int    nchain    = B * (H / GCH);
        const int    NC        = S / LCH;
        const size_t rec       = (size_t)nchain * NC;
        const size_t flagBytes = rec * sizeof(int);
        const size_t flagOff   = (flagBytes + 1023) & ~(size_t)1023;
        const size_t planeElems= rec * GCH;
        const size_t need      = flagOff + 6 * planeElems * sizeof(float);
        if (ws_size >= need) {
            int*   flags = (int*)d_ws;
            float* base0 = (float*)((char*)d_ws + flagOff);
            float* agm = base0;
            float* agn = agm + planeElems;
            float* agd = agn + planeElems;
            float* icm = agd + planeElems;
            float* icn = icm + planeElems;
            float* icd = icn + planeElems;
            (void)hipMemsetAsync(flags, 0, flagBytes, stream);
            wkv_fwd_lb<<<(int)rec, THR, 0, stream>>>(
                time_decay, key, time_first, value,
                max_state, num_state, den_state,
                out, m_out, n_out, dn_out,
                flags, agm, agn, agd, icm, icn, icd,
                B, S, H, nchain, NC);
            launched = true;
        }
    }
    if (!launched && (H % 32 == 0) && (S % BTILE == 0)) {
        const int grid = BH / 32;
        wkv_fwd_blocked<<<grid, 512, 0, stream>>>(time_decay, key, time_first, value,
                                                  max_state, num_state, den_state,
                                                  out, m_out, n_out, dn_out, B, S, H);
        launched = true;
    }
    if (!launched) {
        const int grid = (BH + 63) / 64;
        wkv_fwd_serial<<<grid, 64, 0, stream>>>(time_decay, key, time_first, value,
                                                max_state, num_state, den_state,
                                                out, m_out, n_out, dn_out, B, S, H);
    }
}

// Round 8
// 527.543 us; speedup vs baseline: 2.1650x; 2.1650x over previous
//
#include <hip/hip_runtime.h>

// RWKV WKV forward — R12: R7 base + XCD-chunked swizzle + depth-2 prefetch
// + non-temporal output stores.
//
// Identity: with P=(num,den) scaled by 2^m, the step is the linear recurrence
// P' = 2^{tds} P + 2^{kts} (v,1), decay channel-constant => associative.
// Block = 1024 thr (16 waves) owns 64 contiguous channels (lane = channel);
// sequence in tiles of 128 steps, wave w owns steps [w*8,(w+1)*8).
//
// Evidence so far: R5-R9 (5 structures) all pin at ~403 MB serviced /
// ~125 us ~= 3.1-3.25 TB/s; VALUBusy ~34%. Surviving model: per-CU BW =
// (HW outstanding-line cap x 128 B) / DRAM latency; our 256-B chunks at
// 8-KiB stride get ~2x page-miss latency vs streaming -> ~half of m13's
// 24.6 GB/s/CU. R12 probes latency/page locality:
//  * XCD-chunked bid swizzle (grid%8==0): each batch's 32 channel-group
//    blocks land on ONE XCD -> requests covering an 8-KiB DRAM row
//    cluster in one L2 miss queue -> better page-open locality.
//  * Triple-buffered register prefetch (issue tile it+2 at body(it)) ->
//    2 tile-periods of latency tolerance, 2x software outstanding.
//  * __builtin_nontemporal_store for out (never re-read) -> keeps the
//    write stream out of L2/LLC, frees LLC for k/v re-reads.

#define TILE 128
#define NW   16
#define SUB  (TILE / NW)   // 8

#define BARR  asm volatile("s_waitcnt lgkmcnt(0)\n\ts_barrier" ::: "memory")

__device__ __forceinline__ float ex2(float x)  { return __builtin_amdgcn_exp2f(x); }
__device__ __forceinline__ float rcpf(float x) { return __builtin_amdgcn_rcpf(x); }

__global__ __launch_bounds__(1024, 4)
void wkv_fwd(const float* __restrict__ td_in, const float* __restrict__ kin,
             const float* __restrict__ tf_in, const float* __restrict__ vin,
             const float* __restrict__ m0, const float* __restrict__ n0,
             const float* __restrict__ d0,
             float* __restrict__ out, float* __restrict__ m_out,
             float* __restrict__ n_out, float* __restrict__ dn_out,
             int B, int S, int H)
{
    __shared__ float smry[2][NW][3][64];     // 24 KiB (double-buffered)
    __shared__ float cry[2][3][64];          // 1.5 KiB

    const int tid  = threadIdx.x;
    const int lane = tid & 63;
    const int w    = tid >> 6;               // wave id 0..15

    // XCD-chunked swizzle (bijective when grid % 8 == 0): physical block p
    // runs on XCD p%8; logical work id (p%8)*cpx + p/8 gives XCD x the
    // contiguous logical range [x*cpx, (x+1)*cpx) — for this shape, one
    // full batch (32 channel groups) per XCD.
    const int nwg = gridDim.x;
    int bid = blockIdx.x;
    if ((nwg & 7) == 0) {
        const int cpx = nwg >> 3;
        bid = (blockIdx.x & 7) * cpx + (blockIdx.x >> 3);
    }

    const int bpb = H >> 6;                  // blocks per batch
    const int b   = bid / bpb;
    const int hb  = (bid - b * bpb) << 6;
    const int h   = hb + lane;
    const int g   = b * H + h;

    constexpr float Cc = 1.4426950408889634f;   // log2(e)
    constexpr float IC = 0.6931471805599453f;   // ln(2)

    const float tds  = -ex2(td_in[h] * Cc) * Cc;  // per-step decay, log2 units
    const float tfs  = tf_in[h] * Cc;
    const float dseg = tds * (float)SUB;          // decay over one sub-segment

    if (w == 0) {                                 // tile-0 carry = init state
        cry[0][0][lane] = m0[g] * Cc;
        cry[0][1][lane] = n0[g];
        cry[0][2][lane] = d0[g];
    }

    const size_t base = (size_t)b * (size_t)S * (size_t)H + (size_t)hb;
    const float* gk = kin + base;
    const float* gv = vin + base;
    float*       go = out + base;

    const int ntiles = S / TILE;

    float fM = 0.f, fN = 0.f, fD = 0.f;           // wave15 final state

    // Register triple-buffers for this wave's 8 (k,v) rows.
    float ka[SUB], va[SUB], kb[SUB], vb[SUB], kc[SUB], vc[SUB];

    // Prologue: issue loads for tile 0 -> set A, tile 1 -> set B.
    {
        const size_t t0 = (size_t)w * SUB;
        #pragma unroll
        for (int j = 0; j < SUB; ++j) {
            ka[j] = gk[(t0 + j) * (size_t)H + lane];
            va[j] = gv[(t0 + j) * (size_t)H + lane];
        }
        if (ntiles > 1) {
            const size_t t1 = (size_t)TILE + (size_t)w * SUB;
            #pragma unroll
            for (int j = 0; j < SUB; ++j) {
                kb[j] = gk[(t1 + j) * (size_t)H + lane];
                vb[j] = gv[(t1 + j) * (size_t)H + lane];
            }
        }
    }

    // body(it): compute tile it from (ck,cv); issue prefetch of tile it+2
    // into (fk,fv). Tile it+1's loads (issued one body ago) stay in flight.
    auto body = [&](int it, float (&ck)[SUB], float (&cv)[SUB],
                    float (&fk)[SUB], float (&fv)[SUB])
                __attribute__((always_inline)) -> void {
        if (it + 2 < ntiles) {
            const size_t t2 = (size_t)(it + 2) * TILE + (size_t)w * SUB;
            #pragma unroll
            for (int j = 0; j < SUB; ++j) {
                fk[j] = gk[(t2 + j) * (size_t)H + lane];
                fv[j] = gv[(t2 + j) * (size_t)H + lane];
            }
        }

        const int p = it & 1;

        // ---- Phase A: local scan, prefixes kept in registers ----
        float kt[SUB], vt[SUB];
        float plm[SUB - 1], pln[SUB - 1], pld[SUB - 1];
        float lm = -1e30f, ln = 0.f, ld = 0.f;
        #pragma unroll
        for (int j = 0; j < SUB; ++j) {
            kt[j] = ck[j] * Cc;
            vt[j] = cv[j];
            const float mpd = lm + tds;
            const float d   = mpd - kt[j];        // max-trick: one factor is 1
            const float e   = ex2(-fabsf(d));
            const bool  c   = d >= 0.f;
            const float e1  = c ? 1.f : e;
            const float e2  = c ? e : 1.f;
            ln  = e1 * ln  + e2 * vt[j];
            ld  = e1 * ld  + e2;
            lm  = fmaxf(mpd, kt[j]);
            if (j < SUB - 1) { plm[j] = lm; pln[j] = ln; pld[j] = ld; }
        }
        smry[p][w][0][lane] = lm;
        smry[p][w][1][lane] = ln;
        smry[p][w][2][lane] = ld;
        BARR;                                   // the only barrier per tile
                                                // (lgkmcnt only — vmem loads
                                                //  stay in flight across it)

        // ---- Prefix compose: fixed-trip unrolled, wave-uniform guard ----
        float M = cry[p][0][lane];
        float N = cry[p][1][lane];
        float D = cry[p][2][lane];
        #pragma unroll
        for (int j = 0; j < NW - 1; ++j) {
            const float sm = smry[p][j][0][lane];
            const float sn = smry[p][j][1][lane];
            const float sd = smry[p][j][2][lane];
            if (j < w) {
                const float Md = M + dseg;
                const float d  = Md - sm;
                const float e  = ex2(-fabsf(d));
                const bool  c  = d >= 0.f;
                const float a  = c ? 1.f : e;
                const float bb = c ? e : 1.f;
                N = a * N + bb * sn;
                D = a * D + bb * sd;
                M = fmaxf(Md, sm);
            }
        }

        // ---- Wave 15: tile carry via one compose (off the output path) ----
        if (w == NW - 1) {
            const float Md = M + dseg;
            const float d  = Md - lm;
            const float e  = ex2(-fabsf(d));
            const bool  c  = d >= 0.f;
            const float a  = c ? 1.f : e;
            const float bb = c ? e : 1.f;
            fN = a * N + bb * ln;
            fD = a * D + bb * ld;
            fM = fmaxf(Md, lm);
            cry[p ^ 1][0][lane] = fM;
            cry[p ^ 1][1][lane] = fN;
            cry[p ^ 1][2][lane] = fD;
        }

        // ---- Phase B: outputs via one-shot compose — all steps independent,
        //      non-temporal stores (out is never re-read). ----
        float* po = go + ((size_t)it * TILE + (size_t)w * SUB) * (size_t)H;
        {   // j = 0: state before step 0 is exactly (M,N,D)
            const float ktf = kt[0] + tfs;
            const float dd  = M - ktf;
            const float eo  = ex2(-fabsf(dd));
            const bool  co  = dd >= 0.f;
            const float e1o = co ? 1.f : eo;
            const float e2o = co ? eo : 1.f;
            __builtin_nontemporal_store(
                (e1o * N + e2o * vt[0]) * rcpf(fmaf(e1o, D, e2o)), po + lane);
        }
        float Md = M;
        #pragma unroll
        for (int j = 1; j < SUB; ++j) {
            Md += tds;                            // M + j*tds (cheap chain)
            const float sm = plm[j - 1];
            const float dl = Md - sm;
            const float e  = ex2(-fabsf(dl));
            const bool  c  = dl >= 0.f;
            const float a  = c ? 1.f : e;
            const float bb = c ? e : 1.f;
            const float Nc = a * N + bb * pln[j - 1];
            const float Dc = a * D + bb * pld[j - 1];
            const float Mc = fmaxf(Md, sm);
            const float ktf = kt[j] + tfs;
            const float dd  = Mc - ktf;
            const float eo  = ex2(-fabsf(dd));
            const bool  co  = dd >= 0.f;
            const float e1o = co ? 1.f : eo;
            const float e2o = co ? eo : 1.f;
            __builtin_nontemporal_store(
                (e1o * Nc + e2o * vt[j]) * rcpf(fmaf(e1o, Dc, e2o)),
                po + (size_t)j * H + lane);
        }
    };

    // Triple-rotation tile loop: it%3==0 -> (A,*,C); 1 -> (B,*,A); 2 -> (C,*,B).
    int it = 0;
    for (; it + 2 < ntiles; it += 3) {
        body(it,     ka, va, kc, vc);
        body(it + 1, kb, vb, ka, va);
        body(it + 2, kc, vc, kb, vb);
    }
    if (it < ntiles) { body(it, ka, va, kc, vc); ++it; }
    if (it < ntiles) { body(it, kb, vb, ka, va); }

    if (w == NW - 1) {                          // final states
        m_out[g]  = fM * IC;
        n_out[g]  = fN;
        dn_out[g] = fD;
    }
}

// Safety fallback (serial per channel) for shapes the tiled kernel can't take.
__global__ __launch_bounds__(64)
void wkv_fwd_serial(const float* __restrict__ td_in, const float* __restrict__ kin,
                    const float* __restrict__ tf_in, const float* __restrict__ vin,
                    const float* __restrict__ m0, const float* __restrict__ n0,
                    const float* __restrict__ d0,
                    float* __restrict__ out, float* __restrict__ m_out,
                    float* __restrict__ n_out, float* __restrict__ dn_out,
                    int B, int S, int H)
{
    const int g = blockIdx.x * 64 + threadIdx.x;
    if (g >= B * H) return;
    const int b = g / H;
    const int h = g - b * H;
    constexpr float Cc = 1.4426950408889634f, IC = 0.6931471805599453f;
    const float tds = -ex2(td_in[h] * Cc) * Cc;
    const float tfs = tf_in[h] * Cc;
    float M = m0[g] * Cc, N = n0[g], D = d0[g];
    const size_t base = (size_t)b * S * H + h;
    for (int t = 0; t < S; ++t) {
        const float kt  = kin[base + (size_t)t * H] * Cc;
        const float vt  = vin[base + (size_t)t * H];
        const float ktf = kt + tfs;
        const float mo  = fmaxf(M, ktf);
        const float e1o = ex2(M - mo), e2o = ex2(ktf - mo);
        out[base + (size_t)t * H] = (e1o * N + e2o * vt) * rcpf(e1o * D + e2o);
        const float mpd = M + tds;
        const float ms  = fmaxf(mpd, kt);
        const float e1s = ex2(mpd - ms), e2s = ex2(kt - ms);
        N = e1s * N + e2s * vt;
        D = e1s * D + e2s;
        M = ms;
    }
    m_out[g] = M * IC; n_out[g] = N; dn_out[g] = D;
}

extern "C" void kernel_launch(void* const* d_in, const int* in_sizes, int n_in,
                              void* d_out, int out_size, void* d_ws, size_t ws_size,
                              hipStream_t stream)
{
    const float* time_decay = (const float*)d_in[0];
    const float* key        = (const float*)d_in[1];
    const float* time_first = (const float*)d_in[2];
    const float* value      = (const float*)d_in[3];
    const float* max_state  = (const float*)d_in[4];
    const float* num_state  = (const float*)d_in[5];
    const float* den_state  = (const float*)d_in[6];

    const int H  = in_sizes[0];
    const int BH = in_sizes[4];
    const int B  = BH / H;
    const int S  = in_sizes[1] / BH;

    float* out    = (float*)d_out;
    float* m_out  = out + (size_t)B * (size_t)S * (size_t)H;
    float* n_out  = m_out + BH;
    float* dn_out = n_out + BH;

    if ((H % 64 == 0) && (S % TILE == 0)) {
        const int grid = BH / 64;               // 256 blocks, 1/CU
        wkv_fwd<<<grid, 1024, 0, stream>>>(time_decay, key, time_first, value,
                                           max_state, num_state, den_state,
                                           out, m_out, n_out, dn_out, B, S, H);
    } else {
        const int grid = (BH + 63) / 64;
        wkv_fwd_serial<<<grid, 64, 0, stream>>>(time_decay, key, time_first, value,
                                                max_state, num_state, den_state,
                                                out, m_out, n_out, dn_out, B, S, H);
    }
}

// Round 10
// 337.053 us; speedup vs baseline: 3.3885x; 1.5652x over previous
//
#include <hip/hip_runtime.h>

// RWKV WKV forward — R13: verified R7 base + XCD-chunked bid swizzle ONLY.
//
// Identity: with P=(num,den) scaled by 2^m, the step is the linear recurrence
// P' = 2^{tds} P + 2^{kts} (v,1), decay channel-constant => associative.
// Block = 1024 thr (16 waves) owns 64 contiguous channels (lane = channel);
// sequence in tiles of 128 steps, wave w owns steps [w*8,(w+1)*8).
//
// R12 post-mortem: triple-buffer spilled (WRITE 412 MB, dur 330us) —
// confounded. R13 isolates the one zero-cost knob: bijective XCD-chunked
// swizzle bid=(p%8)*(nwg/8)+p/8. With grid=256 and 32 blocks/batch, XCD x
// gets exactly batch x's 32 channel-group blocks; their 256-B chunks tile
// complete 8-KiB DRAM rows through ONE L2 miss queue in a tight window ->
// row-open clustering -> lower latency -> more BW at fixed MSHR count.
// Everything else is bit-identical to R7 (124us, VGPR 64, no spill).

#define TILE 128
#define NW   16
#define SUB  (TILE / NW)   // 8

#define BARR  asm volatile("s_waitcnt lgkmcnt(0)\n\ts_barrier" ::: "memory")

__device__ __forceinline__ float ex2(float x)  { return __builtin_amdgcn_exp2f(x); }
__device__ __forceinline__ float rcpf(float x) { return __builtin_amdgcn_rcpf(x); }

__global__ __launch_bounds__(1024)
void wkv_fwd(const float* __restrict__ td_in, const float* __restrict__ kin,
             const float* __restrict__ tf_in, const float* __restrict__ vin,
             const float* __restrict__ m0, const float* __restrict__ n0,
             const float* __restrict__ d0,
             float* __restrict__ out, float* __restrict__ m_out,
             float* __restrict__ n_out, float* __restrict__ dn_out,
             int B, int S, int H)
{
    __shared__ float smry[2][NW][3][64];     // 24 KiB (double-buffered)
    __shared__ float cry[2][3][64];          // 1.5 KiB

    const int tid  = threadIdx.x;
    const int lane = tid & 63;
    const int w    = tid >> 6;               // wave id 0..15

    // XCD-chunked bijective swizzle (requires grid % 8 == 0): physical
    // block p runs on XCD p%8; logical id (p%8)*cpx + p/8 gives XCD x the
    // contiguous logical range [x*cpx,(x+1)*cpx) — here: one batch per XCD.
    const int nwg = gridDim.x;
    int bid = blockIdx.x;
    if ((nwg & 7) == 0) {
        const int cpx = nwg >> 3;
        bid = (blockIdx.x & 7) * cpx + (blockIdx.x >> 3);
    }

    const int bpb = H >> 6;                  // blocks per batch
    const int b   = bid / bpb;
    const int hb  = (bid - b * bpb) << 6;
    const int h   = hb + lane;
    const int g   = b * H + h;

    constexpr float Cc = 1.4426950408889634f;   // log2(e)
    constexpr float IC = 0.6931471805599453f;   // ln(2)

    const float tds  = -ex2(td_in[h] * Cc) * Cc;  // per-step decay, log2 units
    const float tfs  = tf_in[h] * Cc;
    const float dseg = tds * (float)SUB;          // decay over one sub-segment

    if (w == 0) {                                 // tile-0 carry = init state
        cry[0][0][lane] = m0[g] * Cc;
        cry[0][1][lane] = n0[g];
        cry[0][2][lane] = d0[g];
    }

    const size_t base = (size_t)b * (size_t)S * (size_t)H + (size_t)hb;
    const float* gk = kin + base;
    const float* gv = vin + base;
    float*       go = out + base;

    const int ntiles = S / TILE;

    float fM = 0.f, fN = 0.f, fD = 0.f;           // wave15 final state

    // Register double-buffers for this wave's 8 (k,v) rows.
    float ka[SUB], va[SUB], kb[SUB], vb[SUB];

    // Prologue: issue loads for tile 0 into set A (coalesced 256 B rows).
    {
        const size_t t0 = (size_t)w * SUB;
        #pragma unroll
        for (int j = 0; j < SUB; ++j) {
            ka[j] = gk[(t0 + j) * (size_t)H + lane];
            va[j] = gv[(t0 + j) * (size_t)H + lane];
        }
    }

    auto body = [&](int it, float (&ck)[SUB], float (&cv)[SUB],
                    float (&nk)[SUB], float (&nv)[SUB])
                __attribute__((always_inline)) -> void {
        // ---- Issue-early: prefetch tile it+1 into the other register set.
        // No wait precedes this; the compiler's auto-vmcnt before first use
        // of ck/cv waits only on the older (current) loads.
        if (it + 1 < ntiles) {
            const size_t t1 = (size_t)(it + 1) * TILE + (size_t)w * SUB;
            #pragma unroll
            for (int j = 0; j < SUB; ++j) {
                nk[j] = gk[(t1 + j) * (size_t)H + lane];
                nv[j] = gv[(t1 + j) * (size_t)H + lane];
            }
        }

        const int p = it & 1;

        // ---- Phase A: local scan, prefixes kept in registers ----
        float kt[SUB], vt[SUB];
        float plm[SUB - 1], pln[SUB - 1], pld[SUB - 1];
        float lm = -1e30f, ln = 0.f, ld = 0.f;
        #pragma unroll
        for (int j = 0; j < SUB; ++j) {
            kt[j] = ck[j] * Cc;
            vt[j] = cv[j];
            const float mpd = lm + tds;
            const float d   = mpd - kt[j];        // max-trick: one factor is 1
            const float e   = ex2(-fabsf(d));
            const bool  c   = d >= 0.f;
            const float e1  = c ? 1.f : e;
            const float e2  = c ? e : 1.f;
            ln  = e1 * ln  + e2 * vt[j];
            ld  = e1 * ld  + e2;
            lm  = fmaxf(mpd, kt[j]);
            if (j < SUB - 1) { plm[j] = lm; pln[j] = ln; pld[j] = ld; }
        }
        smry[p][w][0][lane] = lm;
        smry[p][w][1][lane] = ln;
        smry[p][w][2][lane] = ld;
        BARR;                                   // the only barrier per tile
                                                // (lgkmcnt only — vmem loads
                                                //  stay in flight across it)

        // ---- Prefix compose: fixed-trip unrolled, wave-uniform guard ----
        float M = cry[p][0][lane];
        float N = cry[p][1][lane];
        float D = cry[p][2][lane];
        #pragma unroll
        for (int j = 0; j < NW - 1; ++j) {
            const float sm = smry[p][j][0][lane];
            const float sn = smry[p][j][1][lane];
            const float sd = smry[p][j][2][lane];
            if (j < w) {
                const float Md = M + dseg;
                const float d  = Md - sm;
                const float e  = ex2(-fabsf(d));
                const bool  c  = d >= 0.f;
                const float a  = c ? 1.f : e;
                const float bb = c ? e : 1.f;
                N = a * N + bb * sn;
                D = a * D + bb * sd;
                M = fmaxf(Md, sm);
            }
        }

        // ---- Wave 15: tile carry via one compose (off the output path) ----
        if (w == NW - 1) {
            const float Md = M + dseg;
            const float d  = Md - lm;
            const float e  = ex2(-fabsf(d));
            const bool  c  = d >= 0.f;
            const float a  = c ? 1.f : e;
            const float bb = c ? e : 1.f;
            fN = a * N + bb * ln;
            fD = a * D + bb * ld;
            fM = fmaxf(Md, lm);
            cry[p ^ 1][0][lane] = fM;
            cry[p ^ 1][1][lane] = fN;
            cry[p ^ 1][2][lane] = fD;
        }

        // ---- Phase B: outputs via one-shot compose — all steps independent -
        float* po = go + ((size_t)it * TILE + (size_t)w * SUB) * (size_t)H;
        {   // j = 0: state before step 0 is exactly (M,N,D)
            const float ktf = kt[0] + tfs;
            const float dd  = M - ktf;
            const float eo  = ex2(-fabsf(dd));
            const bool  co  = dd >= 0.f;
            const float e1o = co ? 1.f : eo;
            const float e2o = co ? eo : 1.f;
            po[lane] = (e1o * N + e2o * vt[0]) * rcpf(fmaf(e1o, D, e2o));
        }
        float Md = M;
        #pragma unroll
        for (int j = 1; j < SUB; ++j) {
            Md += tds;                            // M + j*tds (cheap chain)
            const float sm = plm[j - 1];
            const float dl = Md - sm;
            const float e  = ex2(-fabsf(dl));
            const bool  c  = dl >= 0.f;
            const float a  = c ? 1.f : e;
            const float bb = c ? e : 1.f;
            const float Nc = a * N + bb * pln[j - 1];
            const float Dc = a * D + bb * pld[j - 1];
            const float Mc = fmaxf(Md, sm);
            const float ktf = kt[j] + tfs;
            const float dd  = Mc - ktf;
            const float eo  = ex2(-fabsf(dd));
            const bool  co  = dd >= 0.f;
            const float e1o = co ? 1.f : eo;
            const float e2o = co ? eo : 1.f;
            po[(size_t)j * H + lane] =
                (e1o * Nc + e2o * vt[j]) * rcpf(fmaf(e1o, Dc, e2o));
        }
    };

    int it = 0;
    for (; it + 1 < ntiles; it += 2) {
        body(it,     ka, va, kb, vb);
        body(it + 1, kb, vb, ka, va);
    }
    if (it < ntiles) body(it, ka, va, kb, vb);

    if (w == NW - 1) {                          // final states
        m_out[g]  = fM * IC;
        n_out[g]  = fN;
        dn_out[g] = fD;
    }
}

// Safety fallback (serial per channel) for shapes the tiled kernel can't take.
__global__ __launch_bounds__(64)
void wkv_fwd_serial(const float* __restrict__ td_in, const float* __restrict__ kin,
                    const float* __restrict__ tf_in, const float* __restrict__ vin,
                    const float* __restrict__ m0, const float* __restrict__ n0,
                    const float* __restrict__ d0,
                    float* __restrict__ out, float* __restrict__ m_out,
                    float* __restrict__ n_out, float* __restrict__ dn_out,
                    int B, int S, int H)
{
    const int g = blockIdx.x * 64 + threadIdx.x;
    if (g >= B * H) return;
    const int b = g / H;
    const int h = g - b * H;
    constexpr float Cc = 1.4426950408889634f, IC = 0.6931471805599453f;
    const float tds = -ex2(td_in[h] * Cc) * Cc;
    const float tfs = tf_in[h] * Cc;
    float M = m0[g] * Cc, N = n0[g], D = d0[g];
    const size_t base = (size_t)b * S * H + h;
    for (int t = 0; t < S; ++t) {
        const float kt  = kin[base + (size_t)t * H] * Cc;
        const float vt  = vin[base + (size_t)t * H];
        const float ktf = kt + tfs;
        const float mo  = fmaxf(M, ktf);
        const float e1o = ex2(M - mo), e2o = ex2(ktf - mo);
        out[base + (size_t)t * H] = (e1o * N + e2o * vt) * rcpf(e1o * D + e2o);
        const float mpd = M + tds;
        const float ms  = fmaxf(mpd, kt);
        const float e1s = ex2(mpd - ms), e2s = ex2(kt - ms);
        N = e1s * N + e2s * vt;
        D = e1s * D + e2s;
        M = ms;
    }
    m_out[g] = M * IC; n_out[g] = N; dn_out[g] = D;
}

extern "C" void kernel_launch(void* const* d_in, const int* in_sizes, int n_in,
                              void* d_out, int out_size, void* d_ws, size_t ws_size,
                              hipStream_t stream)
{
    const float* time_decay = (const float*)d_in[0];
    const float* key        = (const float*)d_in[1];
    const float* time_first = (const float*)d_in[2];
    const float* value      = (const float*)d_in[3];
    const float* max_state  = (const float*)d_in[4];
    const float* num_state  = (const float*)d_in[5];
    const float* den_state  = (const float*)d_in[6];

    const int H  = in_sizes[0];
    const int BH = in_sizes[4];
    const int B  = BH / H;
    const int S  = in_sizes[1] / BH;

    float* out    = (float*)d_out;
    float* m_out  = out + (size_t)B * (size_t)S * (size_t)H;
    float* n_out  = m_out + BH;
    float* dn_out = n_out + BH;

    if ((H % 64 == 0) && (S % TILE == 0)) {
        const int grid = BH / 64;               // 256 blocks, 1/CU
        wkv_fwd<<<grid, 1024, 0, stream>>>(time_decay, key, time_first, value,
                                           max_state, num_state, den_state,
                                           out, m_out, n_out, dn_out, B, S, H);
    } else {
        const int grid = (BH + 63) / 64;
        wkv_fwd_serial<<<grid, 64, 0, stream>>>(time_decay, key, time_first, value,
                                                max_state, num_state, den_state,
                                                out, m_out, n_out, dn_out, B, S, H);
    }
}